// Round 9
// baseline (1268.880 us; speedup 1.0000x reference)
//
#include <hip/hip_runtime.h>

// Attention (B=4, T=2048, dim=2048, H=16, hd=128) on gfx950.
// Pipeline: prep (casts + cos/sin table, 1 launch) | fused QKV gemm (RoPE epilogue) |
//           flash attention | out gemm.
// R11: (1) flash LDS 96->80KB (K single-buffered, staged right after a raw s_barrier
//      at end of QK; V stays double-buffered) -> 2 blocks/CU, launch_bounds(512,4).
//      (2) exp2-domain softmax (fma+v_exp; NO defer branch). (3) 5 casts + cs_table
//      merged into one prep launch. GEMMs unchanged from R10 (verified 877/810 TF).
// Workspace layout (192 MiB):
//   xb[2^24] wqb wkb wvb wob[2^22 each] qb[2^24] kb[2^24] vtb[2^24] ab[2^24]  (bf16)
//   cs-table (1 MiB float2[2048][64]) aliases ab (dead until flash writes it).

using floatx4  = __attribute__((ext_vector_type(4))) float;
using short8   = __attribute__((ext_vector_type(8))) short;
using ushortx4 = __attribute__((ext_vector_type(4))) unsigned short;

#define DEVFN static __device__ __forceinline__

DEVFN unsigned short f2bf(float f) {          // RNE float->bf16
  unsigned u = __builtin_bit_cast(unsigned, f);
  u += 0x7fffu + ((u >> 16) & 1u);
  return (unsigned short)(u >> 16);
}
DEVFN float bf2f(unsigned short h) {
  return __builtin_bit_cast(float, ((unsigned)h) << 16);
}

DEVFN void async_cp16(const unsigned short* g, unsigned short* l) {
  __builtin_amdgcn_global_load_lds(
      (const __attribute__((address_space(1))) void*)g,
      (__attribute__((address_space(3))) void*)l,
      16, 0, 0);
}

// ---------------- prep: all fp32->bf16 casts + cos/sin table, one launch ------------
__global__ __launch_bounds__(256) void prep_kernel(
    const float4* __restrict__ x, const float4* __restrict__ wq,
    const float4* __restrict__ wk, const float4* __restrict__ wv,
    const float4* __restrict__ wo, const float* __restrict__ pos,
    ushortx4* __restrict__ xb, ushortx4* __restrict__ wqb,
    ushortx4* __restrict__ wkb, ushortx4* __restrict__ wvb,
    ushortx4* __restrict__ wob, float2* __restrict__ cst) {
  int bid = blockIdx.x;
  if (bid < 32768) {
    const float4* in; ushortx4* out; int base;
    if (bid < 16384)      { in = x;  out = xb;  base = 0; }
    else if (bid < 20480) { in = wq; out = wqb; base = 16384; }
    else if (bid < 24576) { in = wk; out = wkb; base = 20480; }
    else if (bid < 28672) { in = wv; out = wvb; base = 24576; }
    else                  { in = wo; out = wob; base = 28672; }
    long u = (long)(bid - base) * 256 + threadIdx.x;
    float4 v = in[u];
    out[u] = (ushortx4){f2bf(v.x), f2bf(v.y), f2bf(v.z), f2bf(v.w)};
  } else {
    int idx = (bid - 32768) * 256 + threadIdx.x;   // 2048*64 entries
    int t = idx >> 6, j = idx & 63;
    float ang = pos[t] * exp2f(-0.20762051f * (float)j);  // 10000^(-j/64)
    cst[idx] = make_float2(cosf(ang), sinf(ang));
  }
}

// ---------------- fused QKV GEMM: C[m,n] = sum_k A[m,k]*W[n,k] + bias[n] ------------
// (unchanged from R10) 256x256 tile, BK=32, 8 waves, triple-buffered LDS, counted
// vmcnt, raw s_barrier. g<2: bf16 [B,H,T,hd] + RoPE. g==2: bf16 [B,H,hd,T].
__global__ __launch_bounds__(512, 2) void qkv_gemm(
    const unsigned short* __restrict__ A,
    const unsigned short* __restrict__ Wq, const unsigned short* __restrict__ Wk,
    const unsigned short* __restrict__ Wv,
    const float* __restrict__ bq, const float* __restrict__ bk,
    const float* __restrict__ bv,
    unsigned short* __restrict__ Oq, unsigned short* __restrict__ Ok,
    unsigned short* __restrict__ Ov,
    const float2* __restrict__ cst) {
  constexpr int K = 2048;
  constexpr int NT = 64;
  __shared__ __align__(16) unsigned short lds[49152];   // 96 KiB: 3 bufs x 16384
  const int tid = threadIdx.x;
  const int wave = tid >> 6, lane = tid & 63;
  const int ln15 = lane & 15, quad = lane >> 4;
  const int wm = wave >> 2, wn = wave & 3;
  const int bid = blockIdx.x;
  const int g = bid >> 8;                        // 0:q 1:k 2:v
  const int b2 = bid & 255;
  const unsigned short* Bw = (g == 0) ? Wq : (g == 1) ? Wk : Wv;
  const float* bias = (g == 0) ? bq : (g == 1) ? bk : bv;
  unsigned short* Cout = (g == 0) ? Oq : (g == 1) ? Ok : Ov;
  const int xcd = b2 & 7, sl = b2 >> 3;
  const int m0 = (xcd * 4 + (sl & 3)) * 256;
  const int n0 = (sl >> 2) * 256;

  const unsigned short *srcA0, *srcA1, *srcB0, *srcB1;
  {
    int u = tid;
    int L = u >> 3, cc = (u & 7) ^ (L & 7);
    int row = L * 2 + (cc >> 2), col = (cc & 3) * 8;
    srcA0 = A + (long)(m0 + row) * K + col;
    srcB0 = Bw + (long)(n0 + row) * K + col;
  }
  {
    int u = tid + 512;
    int L = u >> 3, cc = (u & 7) ^ (L & 7);
    int row = L * 2 + (cc >> 2), col = (cc & 3) * 8;
    srcA1 = A + (long)(m0 + row) * K + col;
    srcB1 = Bw + (long)(n0 + row) * K + col;
  }
  const int sdst = wave * 512;

#define STAGE_G(t, bufp)                                                \
  do {                                                                  \
    async_cp16(srcA0 + (long)(t) * 32, (bufp) + sdst);                  \
    async_cp16(srcA1 + (long)(t) * 32, (bufp) + 4096 + sdst);           \
    async_cp16(srcB0 + (long)(t) * 32, (bufp) + 8192 + sdst);           \
    async_cp16(srcB1 + (long)(t) * 32, (bufp) + 12288 + sdst);          \
  } while (0)

  int offA[8], offB[4];
#pragma unroll
  for (int mi = 0; mi < 8; ++mi) {
    int row = wm * 128 + mi * 16 + ln15;
    int line = row >> 1, cc = (row & 1) * 4 + quad;
    offA[mi] = line * 64 + (cc ^ (line & 7)) * 8;
  }
#pragma unroll
  for (int nj = 0; nj < 4; ++nj) {
    int row = wn * 64 + nj * 16 + ln15;
    int line = row >> 1, cc = (row & 1) * 4 + quad;
    offB[nj] = 8192 + line * 64 + (cc ^ (line & 7)) * 8;
  }

  floatx4 acc[8][4];
#pragma unroll
  for (int i = 0; i < 8; ++i)
#pragma unroll
    for (int j = 0; j < 4; ++j) acc[i][j] = (floatx4){0.f, 0.f, 0.f, 0.f};

  unsigned short* const bA0 = lds;
  unsigned short* const bA1 = lds + 16384;
  unsigned short* const bA2 = lds + 32768;

  STAGE_G(0, bA0);
  STAGE_G(1, bA1);
  asm volatile("s_waitcnt vmcnt(4)" ::: "memory");
  __builtin_amdgcn_s_barrier();

  int cb = 0;
  for (int t = 0; t < NT; ++t) {
    unsigned short* cur = (cb == 0) ? bA0 : ((cb == 1) ? bA1 : bA2);
    if (t < NT - 2) {
      int nb = cb ? cb - 1 : 2;
      unsigned short* nxt = (nb == 0) ? bA0 : ((nb == 1) ? bA1 : bA2);
      STAGE_G(t + 2, nxt);
    }
    short8 af[8], bf4[4];
#pragma unroll
    for (int mi = 0; mi < 8; ++mi) af[mi] = *(const short8*)(cur + offA[mi]);
#pragma unroll
    for (int nj = 0; nj < 4; ++nj) bf4[nj] = *(const short8*)(cur + offB[nj]);
    __builtin_amdgcn_s_setprio(1);
#pragma unroll
    for (int mi = 0; mi < 8; ++mi)
#pragma unroll
      for (int nj = 0; nj < 4; ++nj)
        acc[mi][nj] = __builtin_amdgcn_mfma_f32_16x16x32_bf16(af[mi], bf4[nj],
                                                              acc[mi][nj], 0, 0, 0);
    __builtin_amdgcn_s_setprio(0);
    if (t < NT - 2) {
      asm volatile("s_waitcnt vmcnt(4)" ::: "memory");
    } else if (t == NT - 2) {
      asm volatile("s_waitcnt vmcnt(0)" ::: "memory");
    }
    __builtin_amdgcn_s_barrier();
    cb = (cb == 2) ? 0 : cb + 1;
  }
#undef STAGE_G

  const int b_ = m0 >> 11;
  const int t0m = m0 & 2047;
  const int h0 = n0 >> 7;

  if (g == 2) {
    // V: out [b][h][d][t]. LDS [256 n][128 tl], chunk c=tl>>3, phys = c ^ (n&15)
#pragma unroll
    for (int rnd = 0; rnd < 2; ++rnd) {
      __syncthreads();
      if (wm == rnd) {
#pragma unroll
        for (int nj = 0; nj < 4; ++nj) {
          int nloc = wn * 64 + nj * 16 + ln15;
          float bv = bias[n0 + nloc];
#pragma unroll
          for (int mi = 0; mi < 8; ++mi)
#pragma unroll
            for (int r = 0; r < 4; ++r) {
              int tl = mi * 16 + quad * 4 + r;
              int phys = (tl >> 3) ^ (nloc & 15);
              lds[nloc * 128 + phys * 8 + (tl & 7)] = f2bf(acc[mi][nj][r] + bv);
            }
        }
      }
      __syncthreads();
#pragma unroll
      for (int j = 0; j < 8; ++j) {
        int u = j * 512 + tid;
        int nloc = u >> 4, c = u & 15;
        int phys = c ^ (nloc & 15);
        int h = h0 + (nloc >> 7), d = nloc & 127;
        *(short8*)(Cout +
                   ((((long)(b_ * 16 + h)) << 7) + d) * 2048 + t0m + rnd * 128 + c * 8) =
            *(const short8*)(lds + nloc * 128 + phys * 8);
      }
    }
  } else {
    // Q/K: out [b][h][t][d] with RoPE. LDS [128 tl][256 n], chunk c=n>>3, phys=c^(tl&15)
#pragma unroll
    for (int rnd = 0; rnd < 2; ++rnd) {
      __syncthreads();
      if (wm == rnd) {
#pragma unroll
        for (int nj = 0; nj < 4; ++nj) {
          int nloc = wn * 64 + nj * 16 + ln15;
          float bv = bias[n0 + nloc];
#pragma unroll
          for (int mi = 0; mi < 8; ++mi)
#pragma unroll
            for (int r = 0; r < 4; ++r) {
              int tl = mi * 16 + quad * 4 + r;
              int phys = (nloc >> 3) ^ (tl & 15);
              lds[tl * 256 + phys * 8 + (nloc & 7)] = f2bf(acc[mi][nj][r] + bv);
            }
        }
      }
      __syncthreads();
#pragma unroll
      for (int j = 0; j < 8; ++j) {
        int u = j * 512 + tid;
        int tl = u >> 5, c = u & 31;
        int phys = c ^ (tl & 15);
        int hh = h0 + (c >> 4);
        int tt = t0m + rnd * 128 + tl;
        int cl = c & 15;                            // d0 = cl*8
        int cp = (cl < 8) ? c + 8 : c - 8;          // partner chunk (d +/- 64)
        int physp = cp ^ (tl & 15);
        short8 s8 = *(const short8*)(lds + tl * 256 + phys * 8);
        short8 p8 = *(const short8*)(lds + tl * 256 + physp * 8);
        const float2* ct = cst + tt * 64 + (cl & 7) * 8;
        short8 o8;
#pragma unroll
        for (int e = 0; e < 8; ++e) {
          float2 cs = ct[e];
          float x = bf2f((unsigned short)s8[e]);
          float y = bf2f((unsigned short)p8[e]);
          float v = (cl < 8) ? (x * cs.x - y * cs.y) : (x * cs.x + y * cs.y);
          o8[e] = (short)f2bf(v);
        }
        *(short8*)(Cout + ((((long)(b_ * 16 + hh)) << 11) + tt) * 128 + cl * 8) = o8;
      }
    }
  }
}

// ---------------- output GEMM (wo): fp32 out [M,N] (unchanged from R10) -------------
__global__ __launch_bounds__(512, 2) void gemm_wo(const unsigned short* __restrict__ A,
                                                  const unsigned short* __restrict__ Bw,
                                                  const float* __restrict__ bias,
                                                  float* __restrict__ Cout) {
  constexpr int K = 2048;
  constexpr int NT = 64;
  __shared__ __align__(16) unsigned short lds[49152];
  const int tid = threadIdx.x;
  const int wave = tid >> 6, lane = tid & 63;
  const int ln15 = lane & 15, quad = lane >> 4;
  const int wm = wave >> 2, wn = wave & 3;
  const int bid = blockIdx.x;
  const int xcd = bid & 7, sl = bid >> 3;
  const int m0 = (xcd * 4 + (sl & 3)) * 256;
  const int n0 = (sl >> 2) * 256;

  const unsigned short *srcA0, *srcA1, *srcB0, *srcB1;
  {
    int u = tid;
    int L = u >> 3, cc = (u & 7) ^ (L & 7);
    int row = L * 2 + (cc >> 2), col = (cc & 3) * 8;
    srcA0 = A + (long)(m0 + row) * K + col;
    srcB0 = Bw + (long)(n0 + row) * K + col;
  }
  {
    int u = tid + 512;
    int L = u >> 3, cc = (u & 7) ^ (L & 7);
    int row = L * 2 + (cc >> 2), col = (cc & 3) * 8;
    srcA1 = A + (long)(m0 + row) * K + col;
    srcB1 = Bw + (long)(n0 + row) * K + col;
  }
  const int sdst = wave * 512;

#define STAGE_G(t, bufp)                                                \
  do {                                                                  \
    async_cp16(srcA0 + (long)(t) * 32, (bufp) + sdst);                  \
    async_cp16(srcA1 + (long)(t) * 32, (bufp) + 4096 + sdst);           \
    async_cp16(srcB0 + (long)(t) * 32, (bufp) + 8192 + sdst);           \
    async_cp16(srcB1 + (long)(t) * 32, (bufp) + 12288 + sdst);          \
  } while (0)

  int offA[8], offB[4];
#pragma unroll
  for (int mi = 0; mi < 8; ++mi) {
    int row = wm * 128 + mi * 16 + ln15;
    int line = row >> 1, cc = (row & 1) * 4 + quad;
    offA[mi] = line * 64 + (cc ^ (line & 7)) * 8;
  }
#pragma unroll
  for (int nj = 0; nj < 4; ++nj) {
    int row = wn * 64 + nj * 16 + ln15;
    int line = row >> 1, cc = (row & 1) * 4 + quad;
    offB[nj] = 8192 + line * 64 + (cc ^ (line & 7)) * 8;
  }

  floatx4 acc[8][4];
#pragma unroll
  for (int i = 0; i < 8; ++i)
#pragma unroll
    for (int j = 0; j < 4; ++j) acc[i][j] = (floatx4){0.f, 0.f, 0.f, 0.f};

  unsigned short* const bA0 = lds;
  unsigned short* const bA1 = lds + 16384;
  unsigned short* const bA2 = lds + 32768;

  STAGE_G(0, bA0);
  STAGE_G(1, bA1);
  asm volatile("s_waitcnt vmcnt(4)" ::: "memory");
  __builtin_amdgcn_s_barrier();

  int cb = 0;
  for (int t = 0; t < NT; ++t) {
    unsigned short* cur = (cb == 0) ? bA0 : ((cb == 1) ? bA1 : bA2);
    if (t < NT - 2) {
      int nb = cb ? cb - 1 : 2;
      unsigned short* nxt = (nb == 0) ? bA0 : ((nb == 1) ? bA1 : bA2);
      STAGE_G(t + 2, nxt);
    }
    short8 af[8], bf4[4];
#pragma unroll
    for (int mi = 0; mi < 8; ++mi) af[mi] = *(const short8*)(cur + offA[mi]);
#pragma unroll
    for (int nj = 0; nj < 4; ++nj) bf4[nj] = *(const short8*)(cur + offB[nj]);
    __builtin_amdgcn_s_setprio(1);
#pragma unroll
    for (int mi = 0; mi < 8; ++mi)
#pragma unroll
      for (int nj = 0; nj < 4; ++nj)
        acc[mi][nj] = __builtin_amdgcn_mfma_f32_16x16x32_bf16(af[mi], bf4[nj],
                                                              acc[mi][nj], 0, 0, 0);
    __builtin_amdgcn_s_setprio(0);
    if (t < NT - 2) {
      asm volatile("s_waitcnt vmcnt(4)" ::: "memory");
    } else if (t == NT - 2) {
      asm volatile("s_waitcnt vmcnt(0)" ::: "memory");
    }
    __builtin_amdgcn_s_barrier();
    cb = (cb == 2) ? 0 : cb + 1;
  }
#undef STAGE_G

  float* lf = (float*)lds;
#pragma unroll
  for (int rnd = 0; rnd < 4; ++rnd) {
    __syncthreads();
    if (wm == (rnd >> 1)) {
#pragma unroll
      for (int nj = 0; nj < 4; ++nj) {
        int nloc = wn * 64 + nj * 16 + ln15;
        float bv = bias[n0 + nloc];
#pragma unroll
        for (int mh = 0; mh < 4; ++mh) {
          int mi = (rnd & 1) * 4 + mh;
#pragma unroll
          for (int r = 0; r < 4; ++r) {
            int tl = mh * 16 + quad * 4 + r;
            int phys = (nloc >> 2) ^ (tl & 15);
            lf[tl * 256 + phys * 4 + (nloc & 3)] = acc[mi][nj][r] + bv;
          }
        }
      }
    }
    __syncthreads();
#pragma unroll
    for (int j = 0; j < 8; ++j) {
      int u = j * 512 + tid;
      int tl = u >> 6, c = u & 63;
      int phys = c ^ (tl & 15);
      int m = m0 + rnd * 64 + tl;
      *(floatx4*)(Cout + (long)m * 2048 + n0 + c * 4) =
          *(const floatx4*)(lf + tl * 256 + phys * 4);
    }
  }
}

// ---------------- flash attention (R11: 80KB LDS, 2 blocks/CU, exp2 softmax) --------
// Grid 512, 512 threads (8 waves x 32 q-rows). KVBLK=64.
// LDS: K single 16KB [0,8192) | V dbuf 2x16KB [8192,24576) | P wave-priv [24576,40960).
// Schedule per iter: stage V(t+1)->Valt | QK(t) | raw s_barrier | stage K(t+1)
// (overwrites K; safe: all K reads done) | softmax+P+PV (K latency hides here) |
// vmcnt(0)+barrier. Epilogue O-restage uses lds[0,32768) = 64KB (fits).
__global__ __launch_bounds__(512, 4) void flash_kernel(
    const unsigned short* __restrict__ Q,    // [64][2048][128]
    const unsigned short* __restrict__ Kmat, // [64][2048][128]
    const unsigned short* __restrict__ Vt,   // [64][128][2048]
    unsigned short* __restrict__ Out) {      // [4][2048][2048]
  constexpr int T = 2048;
  constexpr float SL2E = 0.12754228f;        // (1/sqrt(128)) * log2(e)
  __shared__ __align__(16) unsigned short lds[40960];  // 80 KiB

  const int tid = threadIdx.x;
  const int wave = tid >> 6, lane = tid & 63;
  const int ln15 = lane & 15, quad = lane >> 4;
  const int l7 = ln15 & 7;
  const int bid = blockIdx.x;
  const int xcd = bid & 7, sl = bid >> 3;
  const int bh = xcd * 8 + (sl >> 3);
  const int q0 = (sl & 7) * 256;

  const unsigned short* Qb = Q + (long)bh * T * 128;
  const unsigned short* Kb = Kmat + (long)bh * T * 128;
  const unsigned short* Vb = Vt + (long)bh * 128 * T;
  unsigned short* pw = lds + 24576 + wave * 2048;

  short8 qf[2][4];
#pragma unroll
  for (int mi = 0; mi < 2; ++mi)
#pragma unroll
    for (int ks = 0; ks < 4; ++ks)
      qf[mi][ks] = *(const short8*)(Qb + (long)(q0 + wave * 32 + mi * 16 + ln15) * 128 +
                                    ks * 32 + quad * 8);

#define STAGE_K(t)                                                               \
  do {                                                                           \
    _Pragma("unroll") for (int j = 0; j < 2; ++j) {                              \
      int u = j * 512 + tid;                                                     \
      int row = u >> 4;                                                          \
      int c = (u & 15) ^ (row & 15);                                             \
      async_cp16(Kb + (long)((t) * 64 + row) * 128 + c * 8,                      \
                 lds + (j * 512 + wave * 64) * 8);                               \
    }                                                                            \
  } while (0)
#define STAGE_V(t, vdst)                                                         \
  do {                                                                           \
    _Pragma("unroll") for (int j = 0; j < 2; ++j) {                              \
      int u = j * 512 + tid;                                                     \
      int row = u >> 3;                                                          \
      int c = (u & 7) ^ (row & 7);                                               \
      async_cp16(Vb + (long)row * T + (t) * 64 + c * 8,                          \
                 (vdst) + (j * 512 + wave * 64) * 8);                            \
    }                                                                            \
  } while (0)

  STAGE_K(0);
  STAGE_V(0, lds + 8192);
  asm volatile("s_waitcnt vmcnt(0)" ::: "memory");
  __syncthreads();

  floatx4 oacc[2][8];
#pragma unroll
  for (int mi = 0; mi < 2; ++mi)
#pragma unroll
    for (int nj = 0; nj < 8; ++nj) oacc[mi][nj] = (floatx4){0.f, 0.f, 0.f, 0.f};
  float mst[2][4], lsp[2][4];
#pragma unroll
  for (int mi = 0; mi < 2; ++mi)
#pragma unroll
    for (int r = 0; r < 4; ++r) { mst[mi][r] = -1e30f; lsp[mi][r] = 0.f; }

  for (int t = 0; t < 32; ++t) {
    unsigned short* vc = lds + 8192 + (t & 1) * 8192;
    if (t < 31) STAGE_V(t + 1, lds + 8192 + ((t + 1) & 1) * 8192);

    // ---- S = Q K^T from single K buffer
    floatx4 sacc[2][4];
#pragma unroll
    for (int mi = 0; mi < 2; ++mi)
#pragma unroll
      for (int ni = 0; ni < 4; ++ni) sacc[mi][ni] = (floatx4){0.f, 0.f, 0.f, 0.f};
#pragma unroll
    for (int ks = 0; ks < 4; ++ks) {
      short8 bfr[4];
#pragma unroll
      for (int ni = 0; ni < 4; ++ni) {
        int row = ni * 16 + ln15;
        int phys = (ks * 4 + quad) ^ ln15;
        bfr[ni] = *(const short8*)(lds + row * 128 + phys * 8);
      }
      __builtin_amdgcn_s_setprio(1);
#pragma unroll
      for (int mi = 0; mi < 2; ++mi)
#pragma unroll
        for (int ni = 0; ni < 4; ++ni)
          sacc[mi][ni] = __builtin_amdgcn_mfma_f32_16x16x32_bf16(qf[mi][ks], bfr[ni],
                                                                 sacc[mi][ni], 0, 0, 0);
      __builtin_amdgcn_s_setprio(0);
    }

    // all waves done reading K(t); stage K(t+1) over it (no drain here)
    __builtin_amdgcn_s_barrier();
    __builtin_amdgcn_sched_barrier(0);
    if (t < 31) STAGE_K(t + 1);

    // ---- online softmax, exp2 domain (no branch)
#pragma unroll
    for (int mi = 0; mi < 2; ++mi)
#pragma unroll
      for (int r = 0; r < 4; ++r) {
        float mx = fmaxf(fmaxf(sacc[mi][0][r], sacc[mi][1][r]),
                         fmaxf(sacc[mi][2][r], sacc[mi][3][r]));
#pragma unroll
        for (int off = 1; off < 16; off <<= 1) mx = fmaxf(mx, __shfl_xor(mx, off, 16));
        float m2 = mx * SL2E;
        float mold = mst[mi][r];
        float mnew = fmaxf(mold, m2);
        float alpha = exp2f(mold - mnew);
        float rs = 0.f;
#pragma unroll
        for (int ni = 0; ni < 4; ++ni) {
          float p = exp2f(sacc[mi][ni][r] * SL2E - mnew);
          sacc[mi][ni][r] = p;
          rs += p;
        }
        mst[mi][r] = mnew;
        lsp[mi][r] = lsp[mi][r] * alpha + rs;
#pragma unroll
        for (int nj = 0; nj < 8; ++nj) oacc[mi][nj][r] *= alpha;
      }

    // ---- P (bf16) into wave-private buffer
#pragma unroll
    for (int mi = 0; mi < 2; ++mi)
#pragma unroll
      for (int ni = 0; ni < 4; ++ni) {
        int cc = ni * 2 + (ln15 >> 3);
#pragma unroll
        for (int r = 0; r < 4; ++r) {
          int m = mi * 16 + quad * 4 + r;
          pw[m * 64 + (cc ^ (m & 7)) * 8 + l7] = f2bf(sacc[mi][ni][r]);
        }
      }

    // ---- O += P V
#pragma unroll
    for (int ks = 0; ks < 2; ++ks) {
      short8 af[2], bv[8];
#pragma unroll
      for (int mi = 0; mi < 2; ++mi) {
        int phys = (ks * 4 + quad) ^ l7;
        af[mi] = *(const short8*)(pw + (mi * 16 + ln15) * 64 + phys * 8);
      }
#pragma unroll
      for (int nj = 0; nj < 8; ++nj) {
        int row = nj * 16 + ln15;
        int phys = (ks * 4 + quad) ^ (row & 7);
        bv[nj] = *(const short8*)(vc + row * 64 + phys * 8);
      }
      __builtin_amdgcn_s_setprio(1);
#pragma unroll
      for (int mi = 0; mi < 2; ++mi)
#pragma unroll
        for (int nj = 0; nj < 8; ++nj)
          oacc[mi][nj] = __builtin_amdgcn_mfma_f32_16x16x32_bf16(af[mi], bv[nj],
                                                                 oacc[mi][nj], 0, 0, 0);
      __builtin_amdgcn_s_setprio(0);
    }

    // K(t+1) and V(t+1) must be resident before next iter
    asm volatile("s_waitcnt vmcnt(0)" ::: "memory");
    __syncthreads();
  }
#undef STAGE_K
#undef STAGE_V

  float rinv[2][4];
#pragma unroll
  for (int mi = 0; mi < 2; ++mi)
#pragma unroll
    for (int r = 0; r < 4; ++r) {
      float l = lsp[mi][r];
#pragma unroll
      for (int off = 1; off < 16; off <<= 1) l += __shfl_xor(l, off, 16);
      rinv[mi][r] = 1.f / l;
    }
  // O tile [256][128] bf16 = 64KB staged over K/V buffers
#pragma unroll
  for (int mi = 0; mi < 2; ++mi)
#pragma unroll
    for (int nj = 0; nj < 8; ++nj)
#pragma unroll
      for (int r = 0; r < 4; ++r)
        lds[(wave * 32 + mi * 16 + quad * 4 + r) * 128 + nj * 16 + ln15] =
            f2bf(oacc[mi][nj][r] * rinv[mi][r]);
  __syncthreads();
  const int b = bh >> 4, h = bh & 15;
  long obase = ((long)(b * T + q0) << 11) + h * 128;
#pragma unroll
  for (int j = 0; j < 8; ++j) {
    int u = j * 512 + tid;
    int r = u >> 4, c = u & 15;
    *(short8*)(Out + obase + ((long)r << 11) + c * 8) =
        *(const short8*)(lds + r * 128 + c * 8);
  }
}

extern "C" void kernel_launch(void* const* d_in, const int* in_sizes, int n_in,
                              void* d_out, int out_size, void* d_ws, size_t ws_size,
                              hipStream_t stream) {
  const float* x    = (const float*)d_in[0];
  const float* pos  = (const float*)d_in[1];
  const float* wq_w = (const float*)d_in[2];
  const float* wq_b = (const float*)d_in[3];
  const float* wk_w = (const float*)d_in[4];
  const float* wk_b = (const float*)d_in[5];
  const float* wv_w = (const float*)d_in[6];
  const float* wv_b = (const float*)d_in[7];
  const float* wo_w = (const float*)d_in[8];
  const float* wo_b = (const float*)d_in[9];

  unsigned short* xb  = (unsigned short*)d_ws;
  unsigned short* wqb = xb  + (1u << 24);
  unsigned short* wkb = wqb + (1u << 22);
  unsigned short* wvb = wkb + (1u << 22);
  unsigned short* wob = wvb + (1u << 22);
  unsigned short* qb  = wob + (1u << 22);
  unsigned short* kb  = qb  + (1u << 24);
  unsigned short* vtb = kb  + (1u << 24);
  unsigned short* ab  = vtb + (1u << 24);   // attention output, bf16 [8192][2048]
  float2* cst = (float2*)ab;                // cos/sin table aliases ab (dead until flash)

  prep_kernel<<<33280, 256, 0, stream>>>((const float4*)x, (const float4*)wq_w,
                                         (const float4*)wk_w, (const float4*)wv_w,
                                         (const float4*)wo_w, pos,
                                         (ushortx4*)xb, (ushortx4*)wqb, (ushortx4*)wkb,
                                         (ushortx4*)wvb, (ushortx4*)wob, cst);

  qkv_gemm<<<768, 512, 0, stream>>>(xb, wqb, wkb, wvb, wq_b, wk_b, wv_b,
                                    qb, kb, vtb, cst);
  flash_kernel<<<512, 512, 0, stream>>>(qb, kb, vtb, ab);
  gemm_wo<<<256, 512, 0, stream>>>(ab, wob, wo_b, (float*)d_out);
}

// Round 10
// 691.416 us; speedup vs baseline: 1.8352x; 1.8352x over previous
//
#include <hip/hip_runtime.h>

// Attention (B=4, T=2048, dim=2048, H=16, hd=128) on gfx950.
// Pipeline: prep (casts + cos/sin table, 1 launch) | fused QKV gemm (RoPE epilogue) |
//           flash attention | out gemm.
// R12: revert R11's flash occupancy change (launch_bounds(512,4) capped regs at 128
//      but flash needs ~188 arch+acc -> 64 VGPR + 1.8GB scratch spill, 845us).
//      Flash = R10 structure (96KB, (512,2), K/V double-buffered) + exp2-domain
//      softmax only (branch-free, strictly fewer VALU ops). Prep merge kept.
//      GEMMs unchanged from R10 (verified).
// Workspace layout (192 MiB):
//   xb[2^24] wqb wkb wvb wob[2^22 each] qb[2^24] kb[2^24] vtb[2^24] ab[2^24]  (bf16)
//   cs-table (1 MiB float2[2048][64]) aliases ab (dead until flash writes it).

using floatx4  = __attribute__((ext_vector_type(4))) float;
using short8   = __attribute__((ext_vector_type(8))) short;
using ushortx4 = __attribute__((ext_vector_type(4))) unsigned short;

#define DEVFN static __device__ __forceinline__

DEVFN unsigned short f2bf(float f) {          // RNE float->bf16
  unsigned u = __builtin_bit_cast(unsigned, f);
  u += 0x7fffu + ((u >> 16) & 1u);
  return (unsigned short)(u >> 16);
}
DEVFN float bf2f(unsigned short h) {
  return __builtin_bit_cast(float, ((unsigned)h) << 16);
}

DEVFN void async_cp16(const unsigned short* g, unsigned short* l) {
  __builtin_amdgcn_global_load_lds(
      (const __attribute__((address_space(1))) void*)g,
      (__attribute__((address_space(3))) void*)l,
      16, 0, 0);
}

// ---------------- prep: all fp32->bf16 casts + cos/sin table, one launch ------------
__global__ __launch_bounds__(256) void prep_kernel(
    const float4* __restrict__ x, const float4* __restrict__ wq,
    const float4* __restrict__ wk, const float4* __restrict__ wv,
    const float4* __restrict__ wo, const float* __restrict__ pos,
    ushortx4* __restrict__ xb, ushortx4* __restrict__ wqb,
    ushortx4* __restrict__ wkb, ushortx4* __restrict__ wvb,
    ushortx4* __restrict__ wob, float2* __restrict__ cst) {
  int bid = blockIdx.x;
  if (bid < 32768) {
    const float4* in; ushortx4* out; int base;
    if (bid < 16384)      { in = x;  out = xb;  base = 0; }
    else if (bid < 20480) { in = wq; out = wqb; base = 16384; }
    else if (bid < 24576) { in = wk; out = wkb; base = 20480; }
    else if (bid < 28672) { in = wv; out = wvb; base = 24576; }
    else                  { in = wo; out = wob; base = 28672; }
    long u = (long)(bid - base) * 256 + threadIdx.x;
    float4 v = in[u];
    out[u] = (ushortx4){f2bf(v.x), f2bf(v.y), f2bf(v.z), f2bf(v.w)};
  } else {
    int idx = (bid - 32768) * 256 + threadIdx.x;   // 2048*64 entries
    int t = idx >> 6, j = idx & 63;
    float ang = pos[t] * exp2f(-0.20762051f * (float)j);  // 10000^(-j/64)
    cst[idx] = make_float2(cosf(ang), sinf(ang));
  }
}

// ---------------- fused QKV GEMM: C[m,n] = sum_k A[m,k]*W[n,k] + bias[n] ------------
// (unchanged from R10) 256x256 tile, BK=32, 8 waves, triple-buffered LDS, counted
// vmcnt, raw s_barrier. g<2: bf16 [B,H,T,hd] + RoPE. g==2: bf16 [B,H,hd,T].
__global__ __launch_bounds__(512, 2) void qkv_gemm(
    const unsigned short* __restrict__ A,
    const unsigned short* __restrict__ Wq, const unsigned short* __restrict__ Wk,
    const unsigned short* __restrict__ Wv,
    const float* __restrict__ bq, const float* __restrict__ bk,
    const float* __restrict__ bv,
    unsigned short* __restrict__ Oq, unsigned short* __restrict__ Ok,
    unsigned short* __restrict__ Ov,
    const float2* __restrict__ cst) {
  constexpr int K = 2048;
  constexpr int NT = 64;
  __shared__ __align__(16) unsigned short lds[49152];   // 96 KiB: 3 bufs x 16384
  const int tid = threadIdx.x;
  const int wave = tid >> 6, lane = tid & 63;
  const int ln15 = lane & 15, quad = lane >> 4;
  const int wm = wave >> 2, wn = wave & 3;
  const int bid = blockIdx.x;
  const int g = bid >> 8;                        // 0:q 1:k 2:v
  const int b2 = bid & 255;
  const unsigned short* Bw = (g == 0) ? Wq : (g == 1) ? Wk : Wv;
  const float* bias = (g == 0) ? bq : (g == 1) ? bk : bv;
  unsigned short* Cout = (g == 0) ? Oq : (g == 1) ? Ok : Ov;
  const int xcd = b2 & 7, sl = b2 >> 3;
  const int m0 = (xcd * 4 + (sl & 3)) * 256;
  const int n0 = (sl >> 2) * 256;

  const unsigned short *srcA0, *srcA1, *srcB0, *srcB1;
  {
    int u = tid;
    int L = u >> 3, cc = (u & 7) ^ (L & 7);
    int row = L * 2 + (cc >> 2), col = (cc & 3) * 8;
    srcA0 = A + (long)(m0 + row) * K + col;
    srcB0 = Bw + (long)(n0 + row) * K + col;
  }
  {
    int u = tid + 512;
    int L = u >> 3, cc = (u & 7) ^ (L & 7);
    int row = L * 2 + (cc >> 2), col = (cc & 3) * 8;
    srcA1 = A + (long)(m0 + row) * K + col;
    srcB1 = Bw + (long)(n0 + row) * K + col;
  }
  const int sdst = wave * 512;

#define STAGE_G(t, bufp)                                                \
  do {                                                                  \
    async_cp16(srcA0 + (long)(t) * 32, (bufp) + sdst);                  \
    async_cp16(srcA1 + (long)(t) * 32, (bufp) + 4096 + sdst);           \
    async_cp16(srcB0 + (long)(t) * 32, (bufp) + 8192 + sdst);           \
    async_cp16(srcB1 + (long)(t) * 32, (bufp) + 12288 + sdst);          \
  } while (0)

  int offA[8], offB[4];
#pragma unroll
  for (int mi = 0; mi < 8; ++mi) {
    int row = wm * 128 + mi * 16 + ln15;
    int line = row >> 1, cc = (row & 1) * 4 + quad;
    offA[mi] = line * 64 + (cc ^ (line & 7)) * 8;
  }
#pragma unroll
  for (int nj = 0; nj < 4; ++nj) {
    int row = wn * 64 + nj * 16 + ln15;
    int line = row >> 1, cc = (row & 1) * 4 + quad;
    offB[nj] = 8192 + line * 64 + (cc ^ (line & 7)) * 8;
  }

  floatx4 acc[8][4];
#pragma unroll
  for (int i = 0; i < 8; ++i)
#pragma unroll
    for (int j = 0; j < 4; ++j) acc[i][j] = (floatx4){0.f, 0.f, 0.f, 0.f};

  unsigned short* const bA0 = lds;
  unsigned short* const bA1 = lds + 16384;
  unsigned short* const bA2 = lds + 32768;

  STAGE_G(0, bA0);
  STAGE_G(1, bA1);
  asm volatile("s_waitcnt vmcnt(4)" ::: "memory");
  __builtin_amdgcn_s_barrier();

  int cb = 0;
  for (int t = 0; t < NT; ++t) {
    unsigned short* cur = (cb == 0) ? bA0 : ((cb == 1) ? bA1 : bA2);
    if (t < NT - 2) {
      int nb = cb ? cb - 1 : 2;
      unsigned short* nxt = (nb == 0) ? bA0 : ((nb == 1) ? bA1 : bA2);
      STAGE_G(t + 2, nxt);
    }
    short8 af[8], bf4[4];
#pragma unroll
    for (int mi = 0; mi < 8; ++mi) af[mi] = *(const short8*)(cur + offA[mi]);
#pragma unroll
    for (int nj = 0; nj < 4; ++nj) bf4[nj] = *(const short8*)(cur + offB[nj]);
    __builtin_amdgcn_s_setprio(1);
#pragma unroll
    for (int mi = 0; mi < 8; ++mi)
#pragma unroll
      for (int nj = 0; nj < 4; ++nj)
        acc[mi][nj] = __builtin_amdgcn_mfma_f32_16x16x32_bf16(af[mi], bf4[nj],
                                                              acc[mi][nj], 0, 0, 0);
    __builtin_amdgcn_s_setprio(0);
    if (t < NT - 2) {
      asm volatile("s_waitcnt vmcnt(4)" ::: "memory");
    } else if (t == NT - 2) {
      asm volatile("s_waitcnt vmcnt(0)" ::: "memory");
    }
    __builtin_amdgcn_s_barrier();
    cb = (cb == 2) ? 0 : cb + 1;
  }
#undef STAGE_G

  const int b_ = m0 >> 11;
  const int t0m = m0 & 2047;
  const int h0 = n0 >> 7;

  if (g == 2) {
    // V: out [b][h][d][t]. LDS [256 n][128 tl], chunk c=tl>>3, phys = c ^ (n&15)
#pragma unroll
    for (int rnd = 0; rnd < 2; ++rnd) {
      __syncthreads();
      if (wm == rnd) {
#pragma unroll
        for (int nj = 0; nj < 4; ++nj) {
          int nloc = wn * 64 + nj * 16 + ln15;
          float bv = bias[n0 + nloc];
#pragma unroll
          for (int mi = 0; mi < 8; ++mi)
#pragma unroll
            for (int r = 0; r < 4; ++r) {
              int tl = mi * 16 + quad * 4 + r;
              int phys = (tl >> 3) ^ (nloc & 15);
              lds[nloc * 128 + phys * 8 + (tl & 7)] = f2bf(acc[mi][nj][r] + bv);
            }
        }
      }
      __syncthreads();
#pragma unroll
      for (int j = 0; j < 8; ++j) {
        int u = j * 512 + tid;
        int nloc = u >> 4, c = u & 15;
        int phys = c ^ (nloc & 15);
        int h = h0 + (nloc >> 7), d = nloc & 127;
        *(short8*)(Cout +
                   ((((long)(b_ * 16 + h)) << 7) + d) * 2048 + t0m + rnd * 128 + c * 8) =
            *(const short8*)(lds + nloc * 128 + phys * 8);
      }
    }
  } else {
    // Q/K: out [b][h][t][d] with RoPE. LDS [128 tl][256 n], chunk c=n>>3, phys=c^(tl&15)
#pragma unroll
    for (int rnd = 0; rnd < 2; ++rnd) {
      __syncthreads();
      if (wm == rnd) {
#pragma unroll
        for (int nj = 0; nj < 4; ++nj) {
          int nloc = wn * 64 + nj * 16 + ln15;
          float bv = bias[n0 + nloc];
#pragma unroll
          for (int mi = 0; mi < 8; ++mi)
#pragma unroll
            for (int r = 0; r < 4; ++r) {
              int tl = mi * 16 + quad * 4 + r;
              int phys = (nloc >> 3) ^ (tl & 15);
              lds[tl * 256 + phys * 8 + (nloc & 7)] = f2bf(acc[mi][nj][r] + bv);
            }
        }
      }
      __syncthreads();
#pragma unroll
      for (int j = 0; j < 8; ++j) {
        int u = j * 512 + tid;
        int tl = u >> 5, c = u & 31;
        int phys = c ^ (tl & 15);
        int hh = h0 + (c >> 4);
        int tt = t0m + rnd * 128 + tl;
        int cl = c & 15;                            // d0 = cl*8
        int cp = (cl < 8) ? c + 8 : c - 8;          // partner chunk (d +/- 64)
        int physp = cp ^ (tl & 15);
        short8 s8 = *(const short8*)(lds + tl * 256 + phys * 8);
        short8 p8 = *(const short8*)(lds + tl * 256 + physp * 8);
        const float2* ct = cst + tt * 64 + (cl & 7) * 8;
        short8 o8;
#pragma unroll
        for (int e = 0; e < 8; ++e) {
          float2 cs = ct[e];
          float x = bf2f((unsigned short)s8[e]);
          float y = bf2f((unsigned short)p8[e]);
          float v = (cl < 8) ? (x * cs.x - y * cs.y) : (x * cs.x + y * cs.y);
          o8[e] = (short)f2bf(v);
        }
        *(short8*)(Cout + ((((long)(b_ * 16 + hh)) << 11) + tt) * 128 + cl * 8) = o8;
      }
    }
  }
}

// ---------------- output GEMM (wo): fp32 out [M,N] (unchanged from R10) -------------
__global__ __launch_bounds__(512, 2) void gemm_wo(const unsigned short* __restrict__ A,
                                                  const unsigned short* __restrict__ Bw,
                                                  const float* __restrict__ bias,
                                                  float* __restrict__ Cout) {
  constexpr int K = 2048;
  constexpr int NT = 64;
  __shared__ __align__(16) unsigned short lds[49152];
  const int tid = threadIdx.x;
  const int wave = tid >> 6, lane = tid & 63;
  const int ln15 = lane & 15, quad = lane >> 4;
  const int wm = wave >> 2, wn = wave & 3;
  const int bid = blockIdx.x;
  const int xcd = bid & 7, sl = bid >> 3;
  const int m0 = (xcd * 4 + (sl & 3)) * 256;
  const int n0 = (sl >> 2) * 256;

  const unsigned short *srcA0, *srcA1, *srcB0, *srcB1;
  {
    int u = tid;
    int L = u >> 3, cc = (u & 7) ^ (L & 7);
    int row = L * 2 + (cc >> 2), col = (cc & 3) * 8;
    srcA0 = A + (long)(m0 + row) * K + col;
    srcB0 = Bw + (long)(n0 + row) * K + col;
  }
  {
    int u = tid + 512;
    int L = u >> 3, cc = (u & 7) ^ (L & 7);
    int row = L * 2 + (cc >> 2), col = (cc & 3) * 8;
    srcA1 = A + (long)(m0 + row) * K + col;
    srcB1 = Bw + (long)(n0 + row) * K + col;
  }
  const int sdst = wave * 512;

#define STAGE_G(t, bufp)                                                \
  do {                                                                  \
    async_cp16(srcA0 + (long)(t) * 32, (bufp) + sdst);                  \
    async_cp16(srcA1 + (long)(t) * 32, (bufp) + 4096 + sdst);           \
    async_cp16(srcB0 + (long)(t) * 32, (bufp) + 8192 + sdst);           \
    async_cp16(srcB1 + (long)(t) * 32, (bufp) + 12288 + sdst);          \
  } while (0)

  int offA[8], offB[4];
#pragma unroll
  for (int mi = 0; mi < 8; ++mi) {
    int row = wm * 128 + mi * 16 + ln15;
    int line = row >> 1, cc = (row & 1) * 4 + quad;
    offA[mi] = line * 64 + (cc ^ (line & 7)) * 8;
  }
#pragma unroll
  for (int nj = 0; nj < 4; ++nj) {
    int row = wn * 64 + nj * 16 + ln15;
    int line = row >> 1, cc = (row & 1) * 4 + quad;
    offB[nj] = 8192 + line * 64 + (cc ^ (line & 7)) * 8;
  }

  floatx4 acc[8][4];
#pragma unroll
  for (int i = 0; i < 8; ++i)
#pragma unroll
    for (int j = 0; j < 4; ++j) acc[i][j] = (floatx4){0.f, 0.f, 0.f, 0.f};

  unsigned short* const bA0 = lds;
  unsigned short* const bA1 = lds + 16384;
  unsigned short* const bA2 = lds + 32768;

  STAGE_G(0, bA0);
  STAGE_G(1, bA1);
  asm volatile("s_waitcnt vmcnt(4)" ::: "memory");
  __builtin_amdgcn_s_barrier();

  int cb = 0;
  for (int t = 0; t < NT; ++t) {
    unsigned short* cur = (cb == 0) ? bA0 : ((cb == 1) ? bA1 : bA2);
    if (t < NT - 2) {
      int nb = cb ? cb - 1 : 2;
      unsigned short* nxt = (nb == 0) ? bA0 : ((nb == 1) ? bA1 : bA2);
      STAGE_G(t + 2, nxt);
    }
    short8 af[8], bf4[4];
#pragma unroll
    for (int mi = 0; mi < 8; ++mi) af[mi] = *(const short8*)(cur + offA[mi]);
#pragma unroll
    for (int nj = 0; nj < 4; ++nj) bf4[nj] = *(const short8*)(cur + offB[nj]);
    __builtin_amdgcn_s_setprio(1);
#pragma unroll
    for (int mi = 0; mi < 8; ++mi)
#pragma unroll
      for (int nj = 0; nj < 4; ++nj)
        acc[mi][nj] = __builtin_amdgcn_mfma_f32_16x16x32_bf16(af[mi], bf4[nj],
                                                              acc[mi][nj], 0, 0, 0);
    __builtin_amdgcn_s_setprio(0);
    if (t < NT - 2) {
      asm volatile("s_waitcnt vmcnt(4)" ::: "memory");
    } else if (t == NT - 2) {
      asm volatile("s_waitcnt vmcnt(0)" ::: "memory");
    }
    __builtin_amdgcn_s_barrier();
    cb = (cb == 2) ? 0 : cb + 1;
  }
#undef STAGE_G

  float* lf = (float*)lds;
#pragma unroll
  for (int rnd = 0; rnd < 4; ++rnd) {
    __syncthreads();
    if (wm == (rnd >> 1)) {
#pragma unroll
      for (int nj = 0; nj < 4; ++nj) {
        int nloc = wn * 64 + nj * 16 + ln15;
        float bv = bias[n0 + nloc];
#pragma unroll
        for (int mh = 0; mh < 4; ++mh) {
          int mi = (rnd & 1) * 4 + mh;
#pragma unroll
          for (int r = 0; r < 4; ++r) {
            int tl = mh * 16 + quad * 4 + r;
            int phys = (nloc >> 2) ^ (tl & 15);
            lf[tl * 256 + phys * 4 + (nloc & 3)] = acc[mi][nj][r] + bv;
          }
        }
      }
    }
    __syncthreads();
#pragma unroll
    for (int j = 0; j < 8; ++j) {
      int u = j * 512 + tid;
      int tl = u >> 6, c = u & 63;
      int phys = c ^ (tl & 15);
      int m = m0 + rnd * 64 + tl;
      *(floatx4*)(Cout + (long)m * 2048 + n0 + c * 4) =
          *(const floatx4*)(lf + tl * 256 + phys * 4);
    }
  }
}

// ---------------- flash attention (R10 structure + exp2 softmax) ----------------
// Grid 512, 512 threads (8 waves x 32 q-rows). KVBLK=64, K/V gload_lds double-buffered
// (96KB, launch_bounds(512,2) -- R11's (512,4) caused catastrophic spills),
// wave-private P, LDS-staged coalesced output. exp2-domain softmax (branch-free).
__global__ __launch_bounds__(512, 2) void flash_kernel(
    const unsigned short* __restrict__ Q,    // [64][2048][128]
    const unsigned short* __restrict__ Kmat, // [64][2048][128]
    const unsigned short* __restrict__ Vt,   // [64][128][2048]
    unsigned short* __restrict__ Out) {      // [4][2048][2048]
  constexpr int T = 2048;
  constexpr float SL2E = 0.12754228f;        // (1/sqrt(128)) * log2(e)
  __shared__ __align__(16) unsigned short lds[49152];  // 96 KiB

  const int tid = threadIdx.x;
  const int wave = tid >> 6, lane = tid & 63;
  const int ln15 = lane & 15, quad = lane >> 4;
  const int l7 = ln15 & 7;
  const int bid = blockIdx.x;
  const int xcd = bid & 7, sl = bid >> 3;
  const int bh = xcd * 8 + (sl >> 3);
  const int q0 = (sl & 7) * 256;

  const unsigned short* Qb = Q + (long)bh * T * 128;
  const unsigned short* Kb = Kmat + (long)bh * T * 128;
  const unsigned short* Vb = Vt + (long)bh * 128 * T;
  unsigned short* pw = lds + 32768 + wave * 2048;

  short8 qf[2][4];
#pragma unroll
  for (int mi = 0; mi < 2; ++mi)
#pragma unroll
    for (int ks = 0; ks < 4; ++ks)
      qf[mi][ks] = *(const short8*)(Qb + (long)(q0 + wave * 32 + mi * 16 + ln15) * 128 +
                                    ks * 32 + quad * 8);

#define STAGE_KV(t, kdst, vdst)                                                  \
  do {                                                                           \
    _Pragma("unroll") for (int j = 0; j < 2; ++j) {                              \
      int u = j * 512 + tid;                                                     \
      int row = u >> 4;                                                          \
      int c = (u & 15) ^ (row & 15);                                             \
      async_cp16(Kb + (long)((t) * 64 + row) * 128 + c * 8,                      \
                 (kdst) + (j * 512 + wave * 64) * 8);                            \
    }                                                                            \
    _Pragma("unroll") for (int j = 0; j < 2; ++j) {                              \
      int u = j * 512 + tid;                                                     \
      int row = u >> 3;                                                          \
      int c = (u & 7) ^ (row & 7);                                               \
      async_cp16(Vb + (long)row * T + (t) * 64 + c * 8,                          \
                 (vdst) + (j * 512 + wave * 64) * 8);                            \
    }                                                                            \
  } while (0)

  STAGE_KV(0, lds, lds + 16384);
  asm volatile("s_waitcnt vmcnt(0)" ::: "memory");
  __syncthreads();

  floatx4 oacc[2][8];
#pragma unroll
  for (int mi = 0; mi < 2; ++mi)
#pragma unroll
    for (int nj = 0; nj < 8; ++nj) oacc[mi][nj] = (floatx4){0.f, 0.f, 0.f, 0.f};
  float mst[2][4], lsp[2][4];
#pragma unroll
  for (int mi = 0; mi < 2; ++mi)
#pragma unroll
    for (int r = 0; r < 4; ++r) { mst[mi][r] = -1e30f; lsp[mi][r] = 0.f; }

  for (int t = 0; t < 32; ++t) {
    unsigned short* kc = lds + (t & 1) * 8192;
    unsigned short* vc = lds + 16384 + (t & 1) * 8192;
    if (t < 31) {
      unsigned short* kn = lds + ((t + 1) & 1) * 8192;
      unsigned short* vn = lds + 16384 + ((t + 1) & 1) * 8192;
      STAGE_KV(t + 1, kn, vn);
    }

    floatx4 sacc[2][4];
#pragma unroll
    for (int mi = 0; mi < 2; ++mi)
#pragma unroll
      for (int ni = 0; ni < 4; ++ni) sacc[mi][ni] = (floatx4){0.f, 0.f, 0.f, 0.f};
#pragma unroll
    for (int ks = 0; ks < 4; ++ks) {
      short8 bfr[4];
#pragma unroll
      for (int ni = 0; ni < 4; ++ni) {
        int row = ni * 16 + ln15;
        int phys = (ks * 4 + quad) ^ ln15;
        bfr[ni] = *(const short8*)(kc + row * 128 + phys * 8);
      }
      __builtin_amdgcn_s_setprio(1);
#pragma unroll
      for (int mi = 0; mi < 2; ++mi)
#pragma unroll
        for (int ni = 0; ni < 4; ++ni)
          sacc[mi][ni] = __builtin_amdgcn_mfma_f32_16x16x32_bf16(qf[mi][ks], bfr[ni],
                                                                 sacc[mi][ni], 0, 0, 0);
      __builtin_amdgcn_s_setprio(0);
    }

    // online softmax, exp2 domain (branch-free)
#pragma unroll
    for (int mi = 0; mi < 2; ++mi)
#pragma unroll
      for (int r = 0; r < 4; ++r) {
        float mx = fmaxf(fmaxf(sacc[mi][0][r], sacc[mi][1][r]),
                         fmaxf(sacc[mi][2][r], sacc[mi][3][r]));
#pragma unroll
        for (int off = 1; off < 16; off <<= 1) mx = fmaxf(mx, __shfl_xor(mx, off, 16));
        float m2 = mx * SL2E;
        float mold = mst[mi][r];
        float mnew = fmaxf(mold, m2);
        float alpha = exp2f(mold - mnew);
        float rs = 0.f;
#pragma unroll
        for (int ni = 0; ni < 4; ++ni) {
          float p = exp2f(sacc[mi][ni][r] * SL2E - mnew);
          sacc[mi][ni][r] = p;
          rs += p;
        }
        mst[mi][r] = mnew;
        lsp[mi][r] = lsp[mi][r] * alpha + rs;
#pragma unroll
        for (int nj = 0; nj < 8; ++nj) oacc[mi][nj][r] *= alpha;
      }

#pragma unroll
    for (int mi = 0; mi < 2; ++mi)
#pragma unroll
      for (int ni = 0; ni < 4; ++ni) {
        int cc = ni * 2 + (ln15 >> 3);
#pragma unroll
        for (int r = 0; r < 4; ++r) {
          int m = mi * 16 + quad * 4 + r;
          pw[m * 64 + (cc ^ (m & 7)) * 8 + l7] = f2bf(sacc[mi][ni][r]);
        }
      }

#pragma unroll
    for (int ks = 0; ks < 2; ++ks) {
      short8 af[2], bv[8];
#pragma unroll
      for (int mi = 0; mi < 2; ++mi) {
        int phys = (ks * 4 + quad) ^ l7;
        af[mi] = *(const short8*)(pw + (mi * 16 + ln15) * 64 + phys * 8);
      }
#pragma unroll
      for (int nj = 0; nj < 8; ++nj) {
        int row = nj * 16 + ln15;
        int phys = (ks * 4 + quad) ^ (row & 7);
        bv[nj] = *(const short8*)(vc + row * 64 + phys * 8);
      }
      __builtin_amdgcn_s_setprio(1);
#pragma unroll
      for (int mi = 0; mi < 2; ++mi)
#pragma unroll
        for (int nj = 0; nj < 8; ++nj)
          oacc[mi][nj] = __builtin_amdgcn_mfma_f32_16x16x32_bf16(af[mi], bv[nj],
                                                                 oacc[mi][nj], 0, 0, 0);
      __builtin_amdgcn_s_setprio(0);
    }

    asm volatile("s_waitcnt vmcnt(0)" ::: "memory");
    __syncthreads();
  }
#undef STAGE_KV

  float rinv[2][4];
#pragma unroll
  for (int mi = 0; mi < 2; ++mi)
#pragma unroll
    for (int r = 0; r < 4; ++r) {
      float l = lsp[mi][r];
#pragma unroll
      for (int off = 1; off < 16; off <<= 1) l += __shfl_xor(l, off, 16);
      rinv[mi][r] = 1.f / l;
    }
#pragma unroll
  for (int mi = 0; mi < 2; ++mi)
#pragma unroll
    for (int nj = 0; nj < 8; ++nj)
#pragma unroll
      for (int r = 0; r < 4; ++r)
        lds[(wave * 32 + mi * 16 + quad * 4 + r) * 128 + nj * 16 + ln15] =
            f2bf(oacc[mi][nj][r] * rinv[mi][r]);
  __syncthreads();
  const int b = bh >> 4, h = bh & 15;
  long obase = ((long)(b * T + q0) << 11) + h * 128;
#pragma unroll
  for (int j = 0; j < 8; ++j) {
    int u = j * 512 + tid;
    int r = u >> 4, c = u & 15;
    *(short8*)(Out + obase + ((long)r << 11) + c * 8) =
        *(const short8*)(lds + r * 128 + c * 8);
  }
}

extern "C" void kernel_launch(void* const* d_in, const int* in_sizes, int n_in,
                              void* d_out, int out_size, void* d_ws, size_t ws_size,
                              hipStream_t stream) {
  const float* x    = (const float*)d_in[0];
  const float* pos  = (const float*)d_in[1];
  const float* wq_w = (const float*)d_in[2];
  const float* wq_b = (const float*)d_in[3];
  const float* wk_w = (const float*)d_in[4];
  const float* wk_b = (const float*)d_in[5];
  const float* wv_w = (const float*)d_in[6];
  const float* wv_b = (const float*)d_in[7];
  const float* wo_w = (const float*)d_in[8];
  const float* wo_b = (const float*)d_in[9];

  unsigned short* xb  = (unsigned short*)d_ws;
  unsigned short* wqb = xb  + (1u << 24);
  unsigned short* wkb = wqb + (1u << 22);
  unsigned short* wvb = wkb + (1u << 22);
  unsigned short* wob = wvb + (1u << 22);
  unsigned short* qb  = wob + (1u << 22);
  unsigned short* kb  = qb  + (1u << 24);
  unsigned short* vtb = kb  + (1u << 24);
  unsigned short* ab  = vtb + (1u << 24);   // attention output, bf16 [8192][2048]
  float2* cst = (float2*)ab;                // cos/sin table aliases ab (dead until flash)

  prep_kernel<<<33280, 256, 0, stream>>>((const float4*)x, (const float4*)wq_w,
                                         (const float4*)wk_w, (const float4*)wv_w,
                                         (const float4*)wo_w, pos,
                                         (ushortx4*)xb, (ushortx4*)wqb, (ushortx4*)wkb,
                                         (ushortx4*)wvb, (ushortx4*)wob, cst);

  qkv_gemm<<<768, 512, 0, stream>>>(xb, wqb, wkb, wvb, wq_b, wk_b, wv_b,
                                    qb, kb, vtb, cst);
  flash_kernel<<<512, 512, 0, stream>>>(qb, kb, vtb, ab);
  gemm_wo<<<256, 512, 0, stream>>>(ab, wob, wo_b, (float*)d_out);
}